// Round 1
// 766.516 us; speedup vs baseline: 1.0747x; 1.0747x over previous
//
#include <hip/hip_runtime.h>

// GRU_27212912787836 : 2-layer GRU, B=512, T=1024, IN=3, H=64 (fp32 in/out)
// bf16 MFMA internally, fp32 cell math/state.
//
// Round 4: lock-step barrier rounds replace the LDS-atomic spin/release ring.
// 32 blocks x 8 waves (512 thr). Waves 0-3: layer 0; waves 4-7: layer 1
// (lagging exactly one round). h0/h1 exchanged through double-buffered LDS
// slots; ONE raw s_barrier per round (lgkmcnt-only drain via inline asm, so
// global seq_out stores and the x prefetch never drain at step boundaries).
// Round t: L0 computes h0(t) -> h0buf[t&1]; L1 computes h1(t-1) from
// h0buf[(t-1)&1] + its own h1 state -> h1buf[t&1]; barrier; everyone reads
// the freshly published tiles for the next round. WAR is safe: a buffer's
// readers finish (lgkmcnt drained at the next barrier) one full round before
// it is overwritten.
//
// Gate scales folded into weights/biases at load: r,z weights * -log2e,
// n weights * 2*log2e  =>  sigma = rcp(1+exp2(acc)), tanh = 1-2*rcp(1+exp2(acc)).

typedef __attribute__((ext_vector_type(8))) short short8;   // 8 bf16
typedef __attribute__((ext_vector_type(4))) float floatx4;  // MFMA C/D

#define MFMA16(a, b, c) __builtin_amdgcn_mfma_f32_16x16x32_bf16((a), (b), (c), 0, 0, 0)

static constexpr int kB = 512;
static constexpr int kT = 1024;
static constexpr int kIN = 3;
static constexpr int kH = 64;
static constexpr int LDH = 72;  // padded LDS row stride (bf16)
static constexpr float kLog2e = 1.44269504f;

__device__ __forceinline__ unsigned short f2bf(float f) {
  unsigned u = __builtin_bit_cast(unsigned, f);
  return (unsigned short)((u + 0x7FFFu + ((u >> 16) & 1u)) >> 16);
}
__device__ __forceinline__ short8 cvt8s(const float* p, float s) {
  short8 f;
#pragma unroll
  for (int j = 0; j < 8; ++j) f[j] = (short)f2bf(p[j] * s);
  return f;
}

// Raw block barrier: drains LDS ops only. Global stores/loads stay in flight
// (compiler __syncthreads would insert a vmcnt(0) drain -- that's the stall
// the old spin design was built to avoid; this keeps that property).
#define BLOCK_SYNC() asm volatile("s_waitcnt lgkmcnt(0)\n\ts_barrier" ::: "memory")

__global__ __launch_bounds__(512, 2) void gru_kernel(
    const float* __restrict__ x,
    const float* __restrict__ Wih0, const float* __restrict__ Whh0,
    const float* __restrict__ bih0, const float* __restrict__ bhh0,
    const float* __restrict__ Wih1, const float* __restrict__ Whh1,
    const float* __restrict__ bih1, const float* __restrict__ bhh1,
    float* __restrict__ out) {
  const int tid  = threadIdx.x;
  const int lane = tid & 63;
  const int jt   = (tid >> 6) & 3;  // hidden tile 0..3
  const int lyr  = tid >> 8;        // 0: layer0 waves, 1: layer1 waves
  const int c    = lane & 15;
  const int grp  = lane >> 4;
  const int wb   = blockIdx.x * 16;

  __shared__ unsigned short h0buf[2][16 * LDH];  // h0 exchange, double-buffered
  __shared__ unsigned short h1buf[2][16 * LDH];  // h1 exchange, double-buffered

  const int gr = jt * 16 + c, gz = 64 + gr, gn = 128 + gr;
  const float gsc[3] = {-kLog2e, -kLog2e, 2.0f * kLog2e};

  if (lyr == 0) {
    // ================= LAYER-0 stage =================
    short8 whh0[2][3], wx[3];
#pragma unroll
    for (int g = 0; g < 3; ++g) {
      const int off = ((g * 4 + jt) * 16 + c) * kH + grp * 8;
      whh0[0][g] = cvt8s(Whh0 + off, gsc[g]);
      whh0[1][g] = cvt8s(Whh0 + off + 32, gsc[g]);
      short8 f = {0, 0, 0, 0, 0, 0, 0, 0};
      if (grp == 0) {  // W_ih0 is (192 x 3), K zero-padded to 32
        const float* p = Wih0 + ((g * 4 + jt) * 16 + c) * kIN;
        f[0] = (short)f2bf(p[0] * gsc[g]);
        f[1] = (short)f2bf(p[1] * gsc[g]);
        f[2] = (short)f2bf(p[2] * gsc[g]);
      }
      wx[g] = f;
    }
    const float b0r  = -kLog2e * (bih0[gr] + bhh0[gr]);
    const float b0z  = -kLog2e * (bih0[gz] + bhh0[gz]);
    const float b0nx = 2.0f * kLog2e * bih0[gn];
    const float b0nh = 2.0f * kLog2e * bhh0[gn];

    floatx4 h0D = {0.f, 0.f, 0.f, 0.f};
    short8 h0A0 = {0, 0, 0, 0, 0, 0, 0, 0}, h0A1 = h0A0;

    auto load_x = [&](int t) -> short8 {
      short8 f = {0, 0, 0, 0, 0, 0, 0, 0};
      if (grp == 0) {
        const float* p = x + ((size_t)(wb + c) * kT + t) * kIN;
        f[0] = (short)f2bf(p[0]); f[1] = (short)f2bf(p[1]); f[2] = (short)f2bf(p[2]);
      }
      return f;
    };
    short8 xf = load_x(0);

#pragma unroll 1
    for (int t = 0; t <= kT; ++t) {
      if (t < kT) {
        floatx4 ar  = {b0r, b0r, b0r, b0r};
        floatx4 az  = {b0z, b0z, b0z, b0z};
        floatx4 anx = {b0nx, b0nx, b0nx, b0nx};
        floatx4 anh = {b0nh, b0nh, b0nh, b0nh};
        // x-part first (xf ready long ago), then h-part (h0A from last round)
        ar  = MFMA16(xf, wx[0], ar);
        az  = MFMA16(xf, wx[1], az);
        anx = MFMA16(xf, wx[2], anx);
        ar  = MFMA16(h0A0, whh0[0][0], ar);
        ar  = MFMA16(h0A1, whh0[1][0], ar);
        az  = MFMA16(h0A0, whh0[0][1], az);
        az  = MFMA16(h0A1, whh0[1][1], az);
        anh = MFMA16(h0A0, whh0[0][2], anh);
        anh = MFMA16(h0A1, whh0[1][2], anh);

        short8 xn = load_x(t + 1 < kT ? t + 1 : t);  // global prefetch, off-path

        unsigned short* slot = h0buf[t & 1];
#pragma unroll
        for (int r = 0; r < 4; ++r) {
          // gates pre-scaled by the MFMA: sigma = rcp(1+exp2(acc))
          float rg = __builtin_amdgcn_rcpf(1.0f + __builtin_amdgcn_exp2f(ar[r]));
          float zg = __builtin_amdgcn_rcpf(1.0f + __builtin_amdgcn_exp2f(az[r]));
          float u  = __builtin_amdgcn_rcpf(1.0f + __builtin_amdgcn_exp2f(anx[r] + rg * anh[r]));
          float ng = 1.0f - 2.0f * u;          // tanh
          float hn = ng + zg * (h0D[r] - ng);
          h0D[r] = hn;
          slot[(grp * 4 + r) * LDH + jt * 16 + c] = f2bf(hn);
        }
        xf = xn;
      }
      BLOCK_SYNC();
      if (t < kT - 1) {  // publish-read for round t+1
        const unsigned short* s = h0buf[t & 1];
        h0A0 = *(const short8*)(s + c * LDH + grp * 8);
        h0A1 = *(const short8*)(s + c * LDH + 32 + grp * 8);
      }
    }
  } else {
    // ================= LAYER-1 stage (lags one round) =================
    short8 wih1[2][3], whh1[2][3];
#pragma unroll
    for (int g = 0; g < 3; ++g) {
      const int off = ((g * 4 + jt) * 16 + c) * kH + grp * 8;
      wih1[0][g] = cvt8s(Wih1 + off, gsc[g]);
      wih1[1][g] = cvt8s(Wih1 + off + 32, gsc[g]);
      whh1[0][g] = cvt8s(Whh1 + off, gsc[g]);
      whh1[1][g] = cvt8s(Whh1 + off + 32, gsc[g]);
    }
    const float b1r  = -kLog2e * (bih1[gr] + bhh1[gr]);
    const float b1z  = -kLog2e * (bih1[gz] + bhh1[gz]);
    const float b1nx = 2.0f * kLog2e * bih1[gn];
    const float b1nh = 2.0f * kLog2e * bhh1[gn];

    floatx4 h1D = {0.f, 0.f, 0.f, 0.f};
    short8 h1A0 = {0, 0, 0, 0, 0, 0, 0, 0}, h1A1 = h1A0;

    const size_t FH = (size_t)kB * kT * kH;
    float* obase = out + ((size_t)(wb + grp * 4) * kT) * kH + jt * 16 + c;

#pragma unroll 1
    for (int t = 0; t <= kT; ++t) {
      if (t >= 1) {
        // h0(t-1): published before the previous barrier -- read immediately
        const unsigned short* s0 = h0buf[(t - 1) & 1];
        short8 x0 = *(const short8*)(s0 + c * LDH + grp * 8);
        short8 x1 = *(const short8*)(s0 + c * LDH + 32 + grp * 8);

        floatx4 ar  = {b1r, b1r, b1r, b1r};
        floatx4 az  = {b1z, b1z, b1z, b1z};
        floatx4 anx = {b1nx, b1nx, b1nx, b1nx};
        floatx4 anh = {b1nh, b1nh, b1nh, b1nh};
        // h1-part first: operands already in registers, overlaps the s0 reads
        ar  = MFMA16(h1A0, whh1[0][0], ar);
        ar  = MFMA16(h1A1, whh1[1][0], ar);
        az  = MFMA16(h1A0, whh1[0][1], az);
        az  = MFMA16(h1A1, whh1[1][1], az);
        anh = MFMA16(h1A0, whh1[0][2], anh);
        anh = MFMA16(h1A1, whh1[1][2], anh);
        ar  = MFMA16(x0, wih1[0][0], ar);
        ar  = MFMA16(x1, wih1[1][0], ar);
        az  = MFMA16(x0, wih1[0][1], az);
        az  = MFMA16(x1, wih1[1][1], az);
        anx = MFMA16(x0, wih1[0][2], anx);
        anx = MFMA16(x1, wih1[1][2], anx);

        unsigned short* s1 = h1buf[t & 1];
        float hnv[4];
#pragma unroll
        for (int r = 0; r < 4; ++r) {
          float rg = __builtin_amdgcn_rcpf(1.0f + __builtin_amdgcn_exp2f(ar[r]));
          float zg = __builtin_amdgcn_rcpf(1.0f + __builtin_amdgcn_exp2f(az[r]));
          float u  = __builtin_amdgcn_rcpf(1.0f + __builtin_amdgcn_exp2f(anx[r] + rg * anh[r]));
          float ng = 1.0f - 2.0f * u;
          float hn = ng + zg * (h1D[r] - ng);
          h1D[r] = hn;
          s1[(grp * 4 + r) * LDH + jt * 16 + c] = f2bf(hn);
          hnv[r] = hn;
        }

        // seq_out straight from registers; stores stay in flight across the
        // raw barrier (no vmcnt drain anywhere in the loop)
#pragma unroll
        for (int r = 0; r < 4; ++r)
          obase[(size_t)r * kT * kH + (size_t)(t - 1) * kH] = hnv[r];
        if (t == kT) {
#pragma unroll
          for (int r = 0; r < 4; ++r)
            out[FH + (size_t)(wb + grp * 4 + r) * kH + jt * 16 + c] = hnv[r];
        }
      }
      BLOCK_SYNC();
      if (t >= 1 && t < kT) {  // own-layer exchange for round t+1
        const unsigned short* s1r = h1buf[t & 1];
        h1A0 = *(const short8*)(s1r + c * LDH + grp * 8);
        h1A1 = *(const short8*)(s1r + c * LDH + 32 + grp * 8);
      }
    }
  }
}

extern "C" void kernel_launch(void* const* d_in, const int* in_sizes, int n_in,
                              void* d_out, int out_size, void* d_ws, size_t ws_size,
                              hipStream_t stream) {
  const float* xp   = (const float*)d_in[0];
  const float* wih0 = (const float*)d_in[1];
  const float* whh0 = (const float*)d_in[2];
  const float* bih0 = (const float*)d_in[3];
  const float* bhh0 = (const float*)d_in[4];
  const float* wih1 = (const float*)d_in[5];
  const float* whh1 = (const float*)d_in[6];
  const float* bih1 = (const float*)d_in[7];
  const float* bhh1 = (const float*)d_in[8];
  float* outp = (float*)d_out;
  hipLaunchKernelGGL(gru_kernel, dim3(32), dim3(512), 0, stream,
                     xp, wih0, whh0, bih0, bhh0, wih1, whh1, bih1, bhh1, outp);
}

// Round 2
// 531.138 us; speedup vs baseline: 1.5509x; 1.4432x over previous
//
#include <hip/hip_runtime.h>

// GRU_27212912787836 : 2-layer GRU, B=512, T=1024, IN=3, H=64 (fp32 in/out)
// bf16 MFMA internally, fp32 cell math/state.
//
// Round 5: batch re-tile 16 -> 4 per block => 128 blocks / 128 CUs (was 32).
// Rationale: active-CU counters showed MfmaUtil ~22% but VALUBusy ~55% --
// the step was throughput-bound on the transcendental-heavy cell math, not
// on MFMA. Placing the block's 4 batches at MFMA M-rows {0,4,8,12} puts
// exactly ONE valid h-value in every lane (C/D row = (lane>>4)*4+r, so r=0
// only), cutting per-wave VALU/trans work 4x while MFMA count/wave stays
// the same. Unused A-rows stay zero in LDS (zero-initialized once); their
// MFMA outputs are inert bias values that are never consumed.
//
// Sync structure is UNCHANGED from round 4 (verified): one raw s_barrier per
// round, lgkmcnt-only drain, double-buffered LDS h-exchange, L1 lags one
// round. Gate-MFMA accumulation is split into two depth<=2 chains + scalar
// add on component 0 (the only valid one) to shorten the dependent chain.

typedef __attribute__((ext_vector_type(8))) short short8;   // 8 bf16
typedef __attribute__((ext_vector_type(4))) float floatx4;  // MFMA C/D

#define MFMA16(a, b, c) __builtin_amdgcn_mfma_f32_16x16x32_bf16((a), (b), (c), 0, 0, 0)

static constexpr int kB = 512;
static constexpr int kT = 1024;
static constexpr int kIN = 3;
static constexpr int kH = 64;
static constexpr int kBG = 4;   // batches per block (at M-rows 0,4,8,12)
static constexpr int LDH = 72;  // padded LDS row stride in bf16 (16B-aligned rows)
static constexpr float kLog2e = 1.44269504f;

__device__ __forceinline__ unsigned short f2bf(float f) {
  unsigned u = __builtin_bit_cast(unsigned, f);
  return (unsigned short)((u + 0x7FFFu + ((u >> 16) & 1u)) >> 16);
}
__device__ __forceinline__ short8 cvt8s(const float* p, float s) {
  short8 f;
#pragma unroll
  for (int j = 0; j < 8; ++j) f[j] = (short)f2bf(p[j] * s);
  return f;
}

// Raw block barrier: drains LDS ops only; global stores/loads stay in flight.
#define BLOCK_SYNC() asm volatile("s_waitcnt lgkmcnt(0)\n\ts_barrier" ::: "memory")

__global__ __launch_bounds__(512, 2) void gru_kernel(
    const float* __restrict__ x,
    const float* __restrict__ Wih0, const float* __restrict__ Whh0,
    const float* __restrict__ bih0, const float* __restrict__ bhh0,
    const float* __restrict__ Wih1, const float* __restrict__ Whh1,
    const float* __restrict__ bih1, const float* __restrict__ bhh1,
    float* __restrict__ out) {
  const int tid  = threadIdx.x;
  const int lane = tid & 63;
  const int jt   = (tid >> 6) & 3;  // hidden tile 0..3 (16 features each)
  const int lyr  = tid >> 8;        // 0: layer0 waves, 1: layer1 waves
  const int c    = lane & 15;       // feature-in-tile (D col) / batch-row on A reads
  const int grp  = lane >> 4;       // this lane's batch index within the block
  const int wb   = blockIdx.x * kBG;

  __shared__ unsigned short h0buf[2][16 * LDH];  // h0 exchange, double-buffered
  __shared__ unsigned short h1buf[2][16 * LDH];  // h1 exchange, double-buffered

  // Zero-init: rows != 4b are never written and must read as 0 for the MFMA A.
  {
    unsigned short* z0 = &h0buf[0][0];
    unsigned short* z1 = &h1buf[0][0];
    for (int i = tid; i < 2 * 16 * LDH; i += 512) { z0[i] = 0; z1[i] = 0; }
  }
  __syncthreads();  // once, outside the loop

  const int gr = jt * 16 + c, gz = 64 + gr, gn = 128 + gr;
  const float gsc[3] = {-kLog2e, -kLog2e, 2.0f * kLog2e};
  const int myrow = grp * 4;  // this lane's batch lives at M-row 4*grp

  if (lyr == 0) {
    // ================= LAYER-0 stage =================
    short8 whh0[2][3], wx[3];
#pragma unroll
    for (int g = 0; g < 3; ++g) {
      const int off = ((g * 4 + jt) * 16 + c) * kH + grp * 8;
      whh0[0][g] = cvt8s(Whh0 + off, gsc[g]);
      whh0[1][g] = cvt8s(Whh0 + off + 32, gsc[g]);
      short8 f = {0, 0, 0, 0, 0, 0, 0, 0};
      if (grp == 0) {  // W_ih0 is (192 x 3), K zero-padded to 32
        const float* p = Wih0 + ((g * 4 + jt) * 16 + c) * kIN;
        f[0] = (short)f2bf(p[0] * gsc[g]);
        f[1] = (short)f2bf(p[1] * gsc[g]);
        f[2] = (short)f2bf(p[2] * gsc[g]);
      }
      wx[g] = f;
    }
    const float b0r  = -kLog2e * (bih0[gr] + bhh0[gr]);
    const float b0z  = -kLog2e * (bih0[gz] + bhh0[gz]);
    const float b0nx = 2.0f * kLog2e * bih0[gn];
    const float b0nh = 2.0f * kLog2e * bhh0[gn];

    float h0D = 0.f;  // scalar state: one h-value per lane
    short8 h0A0 = {0, 0, 0, 0, 0, 0, 0, 0}, h0A1 = h0A0;

    // x lives in A-rows 4b: only lanes grp==0 (K 0..7) with c%4==0 load it.
    auto load_x = [&](int t) -> short8 {
      short8 f = {0, 0, 0, 0, 0, 0, 0, 0};
      if (grp == 0 && (c & 3) == 0) {
        const float* p = x + ((size_t)(wb + (c >> 2)) * kT + t) * kIN;
        f[0] = (short)f2bf(p[0]); f[1] = (short)f2bf(p[1]); f[2] = (short)f2bf(p[2]);
      }
      return f;
    };
    short8 xf = load_x(0);

#pragma unroll 1
    for (int t = 0; t <= kT; ++t) {
      if (t < kT) {
        // depth<=2 MFMA chains, combine on component 0 only
        floatx4 pr = {b0r, b0r, b0r, b0r};
        pr = MFMA16(xf, wx[0], pr);
        pr = MFMA16(h0A0, whh0[0][0], pr);
        floatx4 qr = {0.f, 0.f, 0.f, 0.f};
        qr = MFMA16(h0A1, whh0[1][0], qr);

        floatx4 pz = {b0z, b0z, b0z, b0z};
        pz = MFMA16(xf, wx[1], pz);
        pz = MFMA16(h0A0, whh0[0][1], pz);
        floatx4 qz = {0.f, 0.f, 0.f, 0.f};
        qz = MFMA16(h0A1, whh0[1][1], qz);

        floatx4 px = {b0nx, b0nx, b0nx, b0nx};
        px = MFMA16(xf, wx[2], px);             // anx, depth 1
        floatx4 ph = {b0nh, b0nh, b0nh, b0nh};
        ph = MFMA16(h0A0, whh0[0][2], ph);
        ph = MFMA16(h0A1, whh0[1][2], ph);      // anh, depth 2

        short8 xn = load_x(t + 1 < kT ? t + 1 : t);  // global prefetch, off-path

        const float ar  = pr[0] + qr[0];
        const float az  = pz[0] + qz[0];
        const float anx = px[0];
        const float anh = ph[0];
        float rg = __builtin_amdgcn_rcpf(1.0f + __builtin_amdgcn_exp2f(ar));
        float zg = __builtin_amdgcn_rcpf(1.0f + __builtin_amdgcn_exp2f(az));
        float u  = __builtin_amdgcn_rcpf(1.0f + __builtin_amdgcn_exp2f(anx + rg * anh));
        float ng = 1.0f - 2.0f * u;              // tanh
        float hn = ng + zg * (h0D - ng);
        h0D = hn;
        h0buf[t & 1][myrow * LDH + jt * 16 + c] = f2bf(hn);
        xf = xn;
      }
      BLOCK_SYNC();
      if (t < kT - 1) {  // published h0(t) -> A-frags for round t+1
        const unsigned short* s = h0buf[t & 1];
        h0A0 = *(const short8*)(s + c * LDH + grp * 8);
        h0A1 = *(const short8*)(s + c * LDH + 32 + grp * 8);
      }
    }
  } else {
    // ================= LAYER-1 stage (lags one round) =================
    short8 wih1[2][3], whh1[2][3];
#pragma unroll
    for (int g = 0; g < 3; ++g) {
      const int off = ((g * 4 + jt) * 16 + c) * kH + grp * 8;
      wih1[0][g] = cvt8s(Wih1 + off, gsc[g]);
      wih1[1][g] = cvt8s(Wih1 + off + 32, gsc[g]);
      whh1[0][g] = cvt8s(Whh1 + off, gsc[g]);
      whh1[1][g] = cvt8s(Whh1 + off + 32, gsc[g]);
    }
    const float b1r  = -kLog2e * (bih1[gr] + bhh1[gr]);
    const float b1z  = -kLog2e * (bih1[gz] + bhh1[gz]);
    const float b1nx = 2.0f * kLog2e * bih1[gn];
    const float b1nh = 2.0f * kLog2e * bhh1[gn];

    float h1D = 0.f;  // scalar state
    short8 h1A0 = {0, 0, 0, 0, 0, 0, 0, 0}, h1A1 = h1A0;

    const size_t FH = (size_t)kB * kT * kH;
    float* obase = out + (size_t)(wb + grp) * kT * kH + jt * 16 + c;

#pragma unroll 1
    for (int t = 0; t <= kT; ++t) {
      if (t >= 1) {
        // h0(t-1): published before the previous barrier
        const unsigned short* s0 = h0buf[(t - 1) & 1];
        short8 x0 = *(const short8*)(s0 + c * LDH + grp * 8);
        short8 x1 = *(const short8*)(s0 + c * LDH + 32 + grp * 8);

        // h1 chains first (register operands, overlap the s0 ds_reads)
        floatx4 pr = {b1r, b1r, b1r, b1r};
        pr = MFMA16(h1A0, whh1[0][0], pr);
        pr = MFMA16(h1A1, whh1[1][0], pr);
        floatx4 pz = {b1z, b1z, b1z, b1z};
        pz = MFMA16(h1A0, whh1[0][1], pz);
        pz = MFMA16(h1A1, whh1[1][1], pz);
        floatx4 pnh = {b1nh, b1nh, b1nh, b1nh};
        pnh = MFMA16(h1A0, whh1[0][2], pnh);
        pnh = MFMA16(h1A1, whh1[1][2], pnh);

        floatx4 qr = {0.f, 0.f, 0.f, 0.f};
        qr = MFMA16(x0, wih1[0][0], qr);
        qr = MFMA16(x1, wih1[1][0], qr);
        floatx4 qz = {0.f, 0.f, 0.f, 0.f};
        qz = MFMA16(x0, wih1[0][1], qz);
        qz = MFMA16(x1, wih1[1][1], qz);
        floatx4 qnx = {b1nx, b1nx, b1nx, b1nx};
        qnx = MFMA16(x0, wih1[0][2], qnx);
        qnx = MFMA16(x1, wih1[1][2], qnx);

        const float ar  = pr[0] + qr[0];
        const float az  = pz[0] + qz[0];
        const float anx = qnx[0];
        const float anh = pnh[0];
        float rg = __builtin_amdgcn_rcpf(1.0f + __builtin_amdgcn_exp2f(ar));
        float zg = __builtin_amdgcn_rcpf(1.0f + __builtin_amdgcn_exp2f(az));
        float u  = __builtin_amdgcn_rcpf(1.0f + __builtin_amdgcn_exp2f(anx + rg * anh));
        float ng = 1.0f - 2.0f * u;
        float hn = ng + zg * (h1D - ng);
        h1D = hn;
        h1buf[t & 1][myrow * LDH + jt * 16 + c] = f2bf(hn);

        // seq_out straight from registers; stays in flight across the barrier
        obase[(size_t)(t - 1) * kH] = hn;
        if (t == kT)
          out[FH + (size_t)(wb + grp) * kH + jt * 16 + c] = hn;
      }
      BLOCK_SYNC();
      if (t >= 1 && t < kT) {  // own-layer exchange for round t+1
        const unsigned short* s1r = h1buf[t & 1];
        h1A0 = *(const short8*)(s1r + c * LDH + grp * 8);
        h1A1 = *(const short8*)(s1r + c * LDH + 32 + grp * 8);
      }
    }
  }
}

extern "C" void kernel_launch(void* const* d_in, const int* in_sizes, int n_in,
                              void* d_out, int out_size, void* d_ws, size_t ws_size,
                              hipStream_t stream) {
  const float* xp   = (const float*)d_in[0];
  const float* wih0 = (const float*)d_in[1];
  const float* whh0 = (const float*)d_in[2];
  const float* bih0 = (const float*)d_in[3];
  const float* bhh0 = (const float*)d_in[4];
  const float* wih1 = (const float*)d_in[5];
  const float* whh1 = (const float*)d_in[6];
  const float* bih1 = (const float*)d_in[7];
  const float* bhh1 = (const float*)d_in[8];
  float* outp = (float*)d_out;
  hipLaunchKernelGGL(gru_kernel, dim3(kB / kBG), dim3(512), 0, stream,
                     xp, wih0, whh0, bih0, bhh0, wih1, whh1, bih1, bhh1, outp);
}